// Round 1
// baseline (266.279 us; speedup 1.0000x reference)
//
#include <hip/hip_runtime.h>

// CrossNet: B=16384, D=1024, 4 layers of:
//   s    = res . w_l                  (per-row dot over D)
//   res  = res + x0 * s + b_l         (rank-1-ish update)
//   res  = (res - mu) * rsqrt(var+eps)  (BatchNorm over batch dim)
//
// Strategy:
//  - BN is per-column affine => carry (scale[d], shift[d]) and apply lazily
//    when the next layer reads the residual (saves a 128MB pass per layer).
//  - Update is row-local => residual lives IN PLACE in d_out.
//  - Column stats: per-block partials -> 2-stage tree reduction (deterministic,
//    short f32 chains).

#define BB 16384
#define DD 1024
#define NL 4
#define BN_EPS 1e-5f

constexpr int ABLK = 1024;                 // layer-kernel grid (4 blocks/CU)
constexpr int ROWS_PER_BLK = BB / ABLK;    // 16 rows per block
constexpr int NB1 = 64;                    // partial rows after stage-0 reduce
constexpr int RED0 = ABLK / NB1;           // 16 partials per stage-0 block

// ---------------------------------------------------------------------------
// Layer kernel: block handles 16 contiguous rows; thread t owns cols [4t,4t+4).
// Per row: lazy-normalize, block-reduce dot(res_norm, w), update, write back,
// accumulate per-column sum/sumsq into registers; dump partials at the end.
// ---------------------------------------------------------------------------
template <bool FIRST>
__global__ __launch_bounds__(256) void layer_kernel(
    const float* __restrict__ x0,   // (B,D) original input
    const float* Rin,               // residual in  (pre-norm; == x for layer 0)
    float*       Rout,              // residual out (pre-norm; may alias Rin)
    const float* __restrict__ w,    // (D)
    const float* __restrict__ bias, // (D)
    const float* __restrict__ scale,// (D) pending BN scale (unused if FIRST)
    const float* __restrict__ shift,// (D) pending BN shift (unused if FIRST)
    float* __restrict__ Psum,       // (ABLK, D) per-block column sums
    float* __restrict__ Psq)        // (ABLK, D) per-block column sumsq
{
    __shared__ float red[2][2][4];  // [slot][row-of-pair][wave]
    const int tid  = threadIdx.x;
    const int lane = tid & 63;
    const int wv   = tid >> 6;
    const int c    = tid << 2;      // column offset of this thread's float4

    const float4 w4 = *(const float4*)(w + c);
    const float4 b4 = *(const float4*)(bias + c);
    float4 sc4, sh4;
    if (FIRST) {
        sc4 = make_float4(1.f, 1.f, 1.f, 1.f);
        sh4 = make_float4(0.f, 0.f, 0.f, 0.f);
    } else {
        sc4 = *(const float4*)(scale + c);
        sh4 = *(const float4*)(shift + c);
    }

    float4 asum = make_float4(0.f, 0.f, 0.f, 0.f);
    float4 asq  = make_float4(0.f, 0.f, 0.f, 0.f);

    const int r0 = blockIdx.x * ROWS_PER_BLK;

    for (int it = 0; it < ROWS_PER_BLK / 2; ++it) {
        const int r = r0 + it * 2;
        const size_t base0 = (size_t)r * DD + c;
        const size_t base1 = base0 + DD;

        // Issue all independent loads up front (4 x 16B in flight).
        float4 v0 = *(const float4*)(Rin + base0);
        float4 v1 = *(const float4*)(Rin + base1);
        float4 xv0, xv1;
        if (!FIRST) {
            xv0 = *(const float4*)(x0 + base0);
            xv1 = *(const float4*)(x0 + base1);
        }

        // Apply pending normalization from the previous layer's BN.
        v0.x = fmaf(v0.x, sc4.x, sh4.x); v0.y = fmaf(v0.y, sc4.y, sh4.y);
        v0.z = fmaf(v0.z, sc4.z, sh4.z); v0.w = fmaf(v0.w, sc4.w, sh4.w);
        v1.x = fmaf(v1.x, sc4.x, sh4.x); v1.y = fmaf(v1.y, sc4.y, sh4.y);
        v1.z = fmaf(v1.z, sc4.z, sh4.z); v1.w = fmaf(v1.w, sc4.w, sh4.w);
        if (FIRST) { xv0 = v0; xv1 = v1; }  // layer 0: x0 row == res row

        // Row dot partials.
        float p0 = v0.x * w4.x + v0.y * w4.y + v0.z * w4.z + v0.w * w4.w;
        float p1 = v1.x * w4.x + v1.y * w4.y + v1.z * w4.z + v1.w * w4.w;

        // Wave-64 butterfly, then cross-wave via LDS (double-buffered slots
        // => single barrier per 2 rows).
        #pragma unroll
        for (int off = 32; off; off >>= 1) {
            p0 += __shfl_down(p0, off, 64);
            p1 += __shfl_down(p1, off, 64);
        }
        const int slot = it & 1;
        if (lane == 0) { red[slot][0][wv] = p0; red[slot][1][wv] = p1; }
        __syncthreads();
        const float s0 = red[slot][0][0] + red[slot][0][1] +
                         red[slot][0][2] + red[slot][0][3];
        const float s1 = red[slot][1][0] + red[slot][1][1] +
                         red[slot][1][2] + red[slot][1][3];

        // res = res_norm + x0*s + b  (pre-norm output of this layer)
        float4 n0, n1;
        n0.x = fmaf(xv0.x, s0, v0.x) + b4.x;
        n0.y = fmaf(xv0.y, s0, v0.y) + b4.y;
        n0.z = fmaf(xv0.z, s0, v0.z) + b4.z;
        n0.w = fmaf(xv0.w, s0, v0.w) + b4.w;
        n1.x = fmaf(xv1.x, s1, v1.x) + b4.x;
        n1.y = fmaf(xv1.y, s1, v1.y) + b4.y;
        n1.z = fmaf(xv1.z, s1, v1.z) + b4.z;
        n1.w = fmaf(xv1.w, s1, v1.w) + b4.w;

        *(float4*)(Rout + base0) = n0;
        *(float4*)(Rout + base1) = n1;

        // Column statistics (thread exclusively owns its 4 columns).
        asum.x += n0.x + n1.x; asum.y += n0.y + n1.y;
        asum.z += n0.z + n1.z; asum.w += n0.w + n1.w;
        asq.x = fmaf(n0.x, n0.x, asq.x); asq.x = fmaf(n1.x, n1.x, asq.x);
        asq.y = fmaf(n0.y, n0.y, asq.y); asq.y = fmaf(n1.y, n1.y, asq.y);
        asq.z = fmaf(n0.z, n0.z, asq.z); asq.z = fmaf(n1.z, n1.z, asq.z);
        asq.w = fmaf(n0.w, n0.w, asq.w); asq.w = fmaf(n1.w, n1.w, asq.w);
    }

    *(float4*)(Psum + (size_t)blockIdx.x * DD + c) = asum;
    *(float4*)(Psq  + (size_t)blockIdx.x * DD + c) = asq;
}

// ---------------------------------------------------------------------------
// Stage-0 partial reduction: (ABLK, D) -> (NB1, D). Coalesced float4 columns.
// ---------------------------------------------------------------------------
__global__ __launch_bounds__(256) void reduce0_kernel(
    const float* __restrict__ Psum, const float* __restrict__ Psq,
    float* __restrict__ Qsum, float* __restrict__ Qsq)
{
    const int c = threadIdx.x << 2;
    const int j = blockIdx.x;
    float4 a = make_float4(0.f, 0.f, 0.f, 0.f);
    float4 q = make_float4(0.f, 0.f, 0.f, 0.f);
    #pragma unroll
    for (int k = 0; k < RED0; ++k) {
        const size_t off = (size_t)(j * RED0 + k) * DD + c;
        const float4 ps = *(const float4*)(Psum + off);
        const float4 pq = *(const float4*)(Psq + off);
        a.x += ps.x; a.y += ps.y; a.z += ps.z; a.w += ps.w;
        q.x += pq.x; q.y += pq.y; q.z += pq.z; q.w += pq.w;
    }
    *(float4*)(Qsum + (size_t)j * DD + c) = a;
    *(float4*)(Qsq  + (size_t)j * DD + c) = q;
}

// ---------------------------------------------------------------------------
// Final stats: (NB1, D) -> scale/shift per column.  mu, biased var, rsqrt.
// ---------------------------------------------------------------------------
__global__ __launch_bounds__(256) void stats_kernel(
    const float* __restrict__ Qsum, const float* __restrict__ Qsq,
    float* __restrict__ scale, float* __restrict__ shift)
{
    const int d = blockIdx.x * 256 + threadIdx.x;   // grid = D/256
    float s = 0.f, q = 0.f;
    #pragma unroll 8
    for (int k = 0; k < NB1; ++k) {
        s += Qsum[k * DD + d];
        q += Qsq[k * DD + d];
    }
    const float mu  = s * (1.0f / BB);
    const float var = q * (1.0f / BB) - mu * mu;
    const float inv = rsqrtf(var + BN_EPS);
    scale[d] = inv;
    shift[d] = -mu * inv;
}

// ---------------------------------------------------------------------------
// Apply the last layer's BN in place on d_out.
// ---------------------------------------------------------------------------
__global__ __launch_bounds__(256) void finalize_kernel(
    float* __restrict__ R,
    const float* __restrict__ scale, const float* __restrict__ shift)
{
    const size_t total = (size_t)BB * DD / 4;
    const size_t stride = (size_t)gridDim.x * blockDim.x;
    for (size_t i = (size_t)blockIdx.x * blockDim.x + threadIdx.x;
         i < total; i += stride) {
        const int c = (int)(i & (DD / 4 - 1)) << 2;
        float4 v = ((const float4*)R)[i];
        const float4 sc = *(const float4*)(scale + c);
        const float4 sh = *(const float4*)(shift + c);
        v.x = fmaf(v.x, sc.x, sh.x);
        v.y = fmaf(v.y, sc.y, sh.y);
        v.z = fmaf(v.z, sc.z, sh.z);
        v.w = fmaf(v.w, sc.w, sh.w);
        ((float4*)R)[i] = v;
    }
}

extern "C" void kernel_launch(void* const* d_in, const int* in_sizes, int n_in,
                              void* d_out, int out_size, void* d_ws, size_t ws_size,
                              hipStream_t stream) {
    const float* x  = (const float*)d_in[0];   // (B, D)
    const float* ww = (const float*)d_in[1];   // (NL, D)
    const float* wb = (const float*)d_in[2];   // (NL, D)
    float* out = (float*)d_out;                // (B, D) residual lives here
    float* ws  = (float*)d_ws;

    // Workspace layout (floats): ~8.5 MB total.
    float* Psum  = ws;                         // ABLK * D
    float* Psq   = Psum + (size_t)ABLK * DD;   // ABLK * D
    float* Qsum  = Psq  + (size_t)ABLK * DD;   // NB1 * D
    float* Qsq   = Qsum + (size_t)NB1 * DD;    // NB1 * D
    float* scale = Qsq  + (size_t)NB1 * DD;    // D
    float* shift = scale + DD;                 // D

    for (int l = 0; l < NL; ++l) {
        const float* w = ww + (size_t)l * DD;
        const float* b = wb + (size_t)l * DD;
        if (l == 0) {
            layer_kernel<true><<<ABLK, 256, 0, stream>>>(
                x, x, out, w, b, scale, shift, Psum, Psq);
        } else {
            layer_kernel<false><<<ABLK, 256, 0, stream>>>(
                x, out, out, w, b, scale, shift, Psum, Psq);
        }
        reduce0_kernel<<<NB1, 256, 0, stream>>>(Psum, Psq, Qsum, Qsq);
        stats_kernel<<<DD / 256, 256, 0, stream>>>(Qsum, Qsq, scale, shift);
    }
    finalize_kernel<<<2048, 256, 0, stream>>>(out, scale, shift);
}